// Round 3
// baseline (259.810 us; speedup 1.0000x reference)
//
#include <hip/hip_runtime.h>
#include <math.h>

#define W 960
#define W4 240
#define NROWS (16 * 544)            // 8704 flat (b,h) rows
#define ROWS_PB 4
#define NBLOCKS (NROWS / ROWS_PB)   // 2176
#define LDS_STRIDE 964              // pad +4 floats, keeps float4 alignment
#define PBV4 (ROWS_PB * W4)         // 960 float4 per block

__device__ __forceinline__ float smooth_l1f(float d) {
    float ad = fabsf(d);
    return ad < 1.0f ? 0.5f * d * d : ad - 0.5f;
}

// ws layout: [0..2] double accumulators (cnt, loss, recon), [3] (byte 24) u32 counter
__global__ __launch_bounds__(256) void loss_kernel(
    const float* __restrict__ dl,
    const float* __restrict__ seg_r,
    const float* __restrict__ dlgt,
    const float* __restrict__ lgt,
    double* __restrict__ ws,
    float* __restrict__ out)
{
    __shared__ float srow[ROWS_PB * LDS_STRIDE];
    const int tid   = threadIdx.x;
    const int base4 = blockIdx.x * PBV4;

    // ---- issue ALL global loads up front (16 float4 in flight / thread) ----
    float4 stg[4], dv4[4], lv4[4], tv4[4];
    #pragma unroll
    for (int j = 0; j < 4; ++j) {
        int t = tid + j * 256;
        if (t < PBV4) stg[j] = ((const float4*)seg_r)[base4 + t];
    }
    #pragma unroll
    for (int j = 0; j < 4; ++j) {
        int t = tid + j * 256;
        if (t < PBV4) {
            dv4[j] = ((const float4*)dl)[base4 + t];
            lv4[j] = ((const float4*)lgt)[base4 + t];
            tv4[j] = ((const float4*)dlgt)[base4 + t];
        }
    }

    // ---- stage seg_r rows into LDS ----
    #pragma unroll
    for (int j = 0; j < 4; ++j) {
        int t = tid + j * 256;
        if (t < PBV4) {
            int r = t / W4;
            int c = t - r * W4;
            float* dst = &srow[r * LDS_STRIDE + (c << 2)];
            float4 v = stg[j];
            dst[0] = v.x; dst[1] = v.y; dst[2] = v.z; dst[3] = v.w;
        }
    }
    __syncthreads();

    // ---- branchless fused loss from registers + LDS gathers ----
    float cnt = 0.f, s_loss = 0.f, s_recon = 0.f;
    #pragma unroll
    for (int j = 0; j < 4; ++j) {
        int t = tid + j * 256;
        if (t < PBV4) {
            int r  = t / W4;
            int c4 = t - r * W4;
            const float* __restrict__ lrow = &srow[r * LDS_STRIDE];
            float dv[4] = {dv4[j].x, dv4[j].y, dv4[j].z, dv4[j].w};
            float lv[4] = {lv4[j].x, lv4[j].y, lv4[j].z, lv4[j].w};
            float tv[4] = {tv4[j].x, tv4[j].y, tv4[j].z, tv4[j].w};
            #pragma unroll
            for (int k = 0; k < 4; ++k) {
                float m = lv[k] > 0.f ? 1.f : 0.f;
                cnt += m;
                float d = dv[k];
                s_loss += m * smooth_l1f(d - tv[k]);

                float sx  = (float)((c4 << 2) + k) - d;
                float x0f = floorf(sx);
                float wx  = sx - x0f;
                int x0 = (int)x0f;
                int x1 = x0 + 1;
                float m0 = (x0 >= 0 && x0 < W) ? 1.f : 0.f;
                float m1 = (x1 >= 0 && x1 < W) ? 1.f : 0.f;
                int x0c = min(max(x0, 0), W - 1);
                int x1c = min(max(x1, 0), W - 1);
                float g0 = lrow[x0c] * m0;
                float g1 = lrow[x1c] * m1;
                float wv = (1.f - wx) * g0 + wx * g1;
                float recon = 1.f / (1.f + __expf(-wv));
                s_recon += m * smooth_l1f(recon - lv[k]);
            }
        }
    }

    // ---- block reduction ----
    double dc = (double)cnt, dlo = (double)s_loss, dre = (double)s_recon;
    for (int off = 32; off > 0; off >>= 1) {
        dc  += __shfl_down(dc,  off, 64);
        dlo += __shfl_down(dlo, off, 64);
        dre += __shfl_down(dre, off, 64);
    }
    __shared__ double sh[3][4];
    int lane = tid & 63, wid = tid >> 6;
    if (lane == 0) { sh[0][wid] = dc; sh[1][wid] = dlo; sh[2][wid] = dre; }
    __syncthreads();

    if (tid == 0) {
        double c = 0, l = 0, r = 0;
        #pragma unroll
        for (int j = 0; j < 4; ++j) { c += sh[0][j]; l += sh[1][j]; r += sh[2][j]; }
        atomicAdd(&ws[0], c);
        atomicAdd(&ws[1], l);
        atomicAdd(&ws[2], r);
        unsigned* cntp = (unsigned*)(ws + 3);
        unsigned prev = __hip_atomic_fetch_add(cntp, 1u, __ATOMIC_ACQ_REL,
                                               __HIP_MEMORY_SCOPE_AGENT);
        if (prev == NBLOCKS - 1) {
            // last block: all other releases happened-before this acquire
            double cc = __hip_atomic_load(&ws[0], __ATOMIC_RELAXED, __HIP_MEMORY_SCOPE_AGENT);
            double ll = __hip_atomic_load(&ws[1], __ATOMIC_RELAXED, __HIP_MEMORY_SCOPE_AGENT);
            double rr = __hip_atomic_load(&ws[2], __ATOMIC_RELAXED, __HIP_MEMORY_SCOPE_AGENT);
            double loss = ll / cc;
            if (isnan(loss)) loss = 0.0;
            out[0] = (float)(loss + 0.5 * (rr / cc));
        }
    }
}

extern "C" void kernel_launch(void* const* d_in, const int* in_sizes, int n_in,
                              void* d_out, int out_size, void* d_ws, size_t ws_size,
                              hipStream_t stream) {
    const float* dl    = (const float*)d_in[0];
    const float* seg_r = (const float*)d_in[1];
    const float* dlgt  = (const float*)d_in[2];
    const float* lgt   = (const float*)d_in[3];
    double* ws = (double*)d_ws;

    // zero 3 double accumulators + u32 counter (ws is re-poisoned to 0xAA)
    hipMemsetAsync(d_ws, 0, 32, stream);
    loss_kernel<<<NBLOCKS, 256, 0, stream>>>(dl, seg_r, dlgt, lgt, ws, (float*)d_out);
}

// Round 4
// 250.555 us; speedup vs baseline: 1.0369x; 1.0369x over previous
//
#include <hip/hip_runtime.h>
#include <math.h>

#define W 960
#define W4 240
#define NROWS (16 * 544)            // 8704 flat (b,h) rows
#define ROWS_PB 4
#define NBLOCKS (NROWS / ROWS_PB)   // 2176
#define TPB 320                     // 5 waves; 960 float4 / 320 = 3 uniform iters
#define ITERS 3
#define LDS_STRIDE 964              // pad +4 floats; keeps 16B alignment (964%4==0)
#define PBV4 (ROWS_PB * W4)         // 960 float4 per block

__device__ __forceinline__ float smooth_l1f(float d) {
    float ad = fabsf(d);
    return ad < 1.0f ? 0.5f * d * d : ad - 0.5f;
}

// ws layout: [0..2] double accumulators (cnt, loss, recon), [3] u32 counter
__global__ __launch_bounds__(TPB) void loss_kernel(
    const float* __restrict__ dl,
    const float* __restrict__ seg_r,
    const float* __restrict__ dlgt,
    const float* __restrict__ lgt,
    double* __restrict__ ws,
    float* __restrict__ out)
{
    __shared__ float srow[ROWS_PB * LDS_STRIDE];
    const int tid   = threadIdx.x;
    const int base4 = blockIdx.x * PBV4;

    // ---- all loads issued up front, NO guards (uniform trip counts) ----
    float4 stg[ITERS];
    #pragma unroll
    for (int j = 0; j < ITERS; ++j)
        stg[j] = ((const float4*)seg_r)[base4 + tid + j * TPB];

    float4 dv4[ITERS], lv4[ITERS], tv4[ITERS];
    #pragma unroll
    for (int j = 0; j < ITERS; ++j) {
        int g = base4 + tid + j * TPB;
        dv4[j] = ((const float4*)dl)[g];
        lv4[j] = ((const float4*)lgt)[g];
        tv4[j] = ((const float4*)dlgt)[g];
    }

    // ---- stage seg_r into LDS (only waits on the 3 staging loads) ----
    #pragma unroll
    for (int j = 0; j < ITERS; ++j) {
        int t = tid + j * TPB;
        int r = t / W4;
        int c = t - r * W4;
        *(float4*)&srow[r * LDS_STRIDE + (c << 2)] = stg[j];
    }
    __syncthreads();

    // ---- branchless fused loss: registers + LDS gathers ----
    float cnt = 0.f, s_loss = 0.f, s_recon = 0.f;
    #pragma unroll
    for (int j = 0; j < ITERS; ++j) {
        int t  = tid + j * TPB;
        int r  = t / W4;
        int c4 = t - r * W4;
        const float* __restrict__ lrow = &srow[r * LDS_STRIDE];
        float dv[4] = {dv4[j].x, dv4[j].y, dv4[j].z, dv4[j].w};
        float lv[4] = {lv4[j].x, lv4[j].y, lv4[j].z, lv4[j].w};
        float tv[4] = {tv4[j].x, tv4[j].y, tv4[j].z, tv4[j].w};
        #pragma unroll
        for (int k = 0; k < 4; ++k) {
            float m = lv[k] > 0.f ? 1.f : 0.f;
            cnt += m;
            float d = dv[k];
            s_loss += m * smooth_l1f(d - tv[k]);

            float sx  = (float)((c4 << 2) + k) - d;
            float x0f = floorf(sx);
            float wx  = sx - x0f;
            int x0 = (int)x0f;
            int x1 = x0 + 1;
            float m0 = (x0 >= 0 && x0 < W) ? 1.f : 0.f;
            float m1 = (x1 >= 0 && x1 < W) ? 1.f : 0.f;
            int x0c = min(max(x0, 0), W - 1);
            int x1c = min(max(x1, 0), W - 1);
            float g0 = lrow[x0c] * m0;
            float g1 = lrow[x1c] * m1;
            float wv = fmaf(wx, g1 - g0, g0);
            float recon = 1.f / (1.f + __expf(-wv));
            s_recon += m * smooth_l1f(recon - lv[k]);
        }
    }

    // ---- block reduction: wave shuffle (double) then LDS across 5 waves ----
    double dc = (double)cnt, dlo = (double)s_loss, dre = (double)s_recon;
    for (int off = 32; off > 0; off >>= 1) {
        dc  += __shfl_down(dc,  off, 64);
        dlo += __shfl_down(dlo, off, 64);
        dre += __shfl_down(dre, off, 64);
    }
    __shared__ double sh[3][TPB / 64];
    int lane = tid & 63, wid = tid >> 6;
    if (lane == 0) { sh[0][wid] = dc; sh[1][wid] = dlo; sh[2][wid] = dre; }
    __syncthreads();

    if (tid == 0) {
        double c = 0, l = 0, r = 0;
        #pragma unroll
        for (int j = 0; j < TPB / 64; ++j) { c += sh[0][j]; l += sh[1][j]; r += sh[2][j]; }
        atomicAdd(&ws[0], c);   // relaxed device-scope, no cache maintenance
        atomicAdd(&ws[1], l);
        atomicAdd(&ws[2], r);
        unsigned* cntp = (unsigned*)(ws + 3);
        // RELEASE only: orders the partial atomics before the increment
        // (waitcnt + tiny L2 writeback). No per-block invalidate.
        unsigned prev = __hip_atomic_fetch_add(cntp, 1u, __ATOMIC_RELEASE,
                                               __HIP_MEMORY_SCOPE_AGENT);
        if (prev == NBLOCKS - 1) {
            __threadfence();    // the ONE acquire in the whole grid
            double cc = __hip_atomic_load(&ws[0], __ATOMIC_RELAXED, __HIP_MEMORY_SCOPE_AGENT);
            double ll = __hip_atomic_load(&ws[1], __ATOMIC_RELAXED, __HIP_MEMORY_SCOPE_AGENT);
            double rr = __hip_atomic_load(&ws[2], __ATOMIC_RELAXED, __HIP_MEMORY_SCOPE_AGENT);
            double loss = ll / cc;
            if (isnan(loss)) loss = 0.0;
            out[0] = (float)(loss + 0.5 * (rr / cc));
        }
    }
}

extern "C" void kernel_launch(void* const* d_in, const int* in_sizes, int n_in,
                              void* d_out, int out_size, void* d_ws, size_t ws_size,
                              hipStream_t stream) {
    const float* dl    = (const float*)d_in[0];
    const float* seg_r = (const float*)d_in[1];
    const float* dlgt  = (const float*)d_in[2];
    const float* lgt   = (const float*)d_in[3];
    double* ws = (double*)d_ws;

    // zero 3 double accumulators + u32 counter (ws is re-poisoned to 0xAA)
    hipMemsetAsync(d_ws, 0, 32, stream);
    loss_kernel<<<NBLOCKS, TPB, 0, stream>>>(dl, seg_r, dlgt, lgt, ws, (float*)d_out);
}

// Round 5
// 156.794 us; speedup vs baseline: 1.6570x; 1.5980x over previous
//
#include <hip/hip_runtime.h>
#include <math.h>

#define W 960
#define W4 240
#define NROWS (16 * 544)            // 8704 flat (b,h) rows
#define ROWS_PB 4
#define NBLOCKS (NROWS / ROWS_PB)   // 2176
#define TPB 320                     // 5 waves; 960 float4 / 320 = 3 uniform iters
#define ITERS 3
#define LDS_STRIDE 964              // pad +4 floats; keeps 16B alignment
#define PBV4 (ROWS_PB * W4)         // 960 float4 per block

__device__ __forceinline__ float smooth_l1f(float d) {
    float ad = fabsf(d);
    return ad < 1.0f ? 0.5f * d * d : ad - 0.5f;
}

// ws layout: per-block slot of 4 doubles (cnt, loss, recon, pad) — NO atomics.
__global__ __launch_bounds__(TPB) void loss_kernel(
    const float* __restrict__ dl,
    const float* __restrict__ seg_r,
    const float* __restrict__ dlgt,
    const float* __restrict__ lgt,
    double* __restrict__ ws)
{
    __shared__ float srow[ROWS_PB * LDS_STRIDE];
    const int tid   = threadIdx.x;
    const int base4 = blockIdx.x * PBV4;

    // ---- all loads issued up front, uniform trip counts, no guards ----
    float4 stg[ITERS];
    #pragma unroll
    for (int j = 0; j < ITERS; ++j)
        stg[j] = ((const float4*)seg_r)[base4 + tid + j * TPB];

    float4 dv4[ITERS], lv4[ITERS], tv4[ITERS];
    #pragma unroll
    for (int j = 0; j < ITERS; ++j) {
        int g = base4 + tid + j * TPB;
        dv4[j] = ((const float4*)dl)[g];
        lv4[j] = ((const float4*)lgt)[g];
        tv4[j] = ((const float4*)dlgt)[g];
    }

    // ---- stage seg_r into LDS ----
    #pragma unroll
    for (int j = 0; j < ITERS; ++j) {
        int t = tid + j * TPB;
        int r = t / W4;
        int c = t - r * W4;
        *(float4*)&srow[r * LDS_STRIDE + (c << 2)] = stg[j];
    }
    __syncthreads();

    // ---- branchless fused loss: registers + LDS gathers ----
    float cnt = 0.f, s_loss = 0.f, s_recon = 0.f;
    #pragma unroll
    for (int j = 0; j < ITERS; ++j) {
        int t  = tid + j * TPB;
        int r  = t / W4;
        int c4 = t - r * W4;
        const float* __restrict__ lrow = &srow[r * LDS_STRIDE];
        float dv[4] = {dv4[j].x, dv4[j].y, dv4[j].z, dv4[j].w};
        float lv[4] = {lv4[j].x, lv4[j].y, lv4[j].z, lv4[j].w};
        float tv[4] = {tv4[j].x, tv4[j].y, tv4[j].z, tv4[j].w};
        #pragma unroll
        for (int k = 0; k < 4; ++k) {
            float m = lv[k] > 0.f ? 1.f : 0.f;
            cnt += m;
            float d = dv[k];
            s_loss += m * smooth_l1f(d - tv[k]);

            float sx  = (float)((c4 << 2) + k) - d;
            float x0f = floorf(sx);
            float wx  = sx - x0f;
            int x0 = (int)x0f;
            int x1 = x0 + 1;
            float m0 = (x0 >= 0 && x0 < W) ? 1.f : 0.f;
            float m1 = (x1 >= 0 && x1 < W) ? 1.f : 0.f;
            int x0c = min(max(x0, 0), W - 1);
            int x1c = min(max(x1, 0), W - 1);
            float g0 = lrow[x0c] * m0;
            float g1 = lrow[x1c] * m1;
            float wv = fmaf(wx, g1 - g0, g0);
            float recon = 1.f / (1.f + __expf(-wv));
            s_recon += m * smooth_l1f(recon - lv[k]);
        }
    }

    // ---- block reduction: wave shuffle (double) then LDS across 5 waves ----
    double dc = (double)cnt, dlo = (double)s_loss, dre = (double)s_recon;
    for (int off = 32; off > 0; off >>= 1) {
        dc  += __shfl_down(dc,  off, 64);
        dlo += __shfl_down(dlo, off, 64);
        dre += __shfl_down(dre, off, 64);
    }
    __shared__ double sh[3][TPB / 64];
    int lane = tid & 63, wid = tid >> 6;
    if (lane == 0) { sh[0][wid] = dc; sh[1][wid] = dlo; sh[2][wid] = dre; }
    __syncthreads();

    if (tid == 0) {
        double c = 0, l = 0, r = 0;
        #pragma unroll
        for (int j = 0; j < TPB / 64; ++j) { c += sh[0][j]; l += sh[1][j]; r += sh[2][j]; }
        double* slot = ws + blockIdx.x * 4;   // plain stores, zero contention
        slot[0] = c; slot[1] = l; slot[2] = r;
    }
}

__global__ __launch_bounds__(256) void finalize_kernel(
    const double* __restrict__ ws, float* __restrict__ out)
{
    double c = 0, l = 0, r = 0;
    for (int i = threadIdx.x; i < NBLOCKS; i += 256) {
        const double* slot = ws + i * 4;
        c += slot[0]; l += slot[1]; r += slot[2];
    }
    for (int off = 32; off > 0; off >>= 1) {
        c += __shfl_down(c, off, 64);
        l += __shfl_down(l, off, 64);
        r += __shfl_down(r, off, 64);
    }
    __shared__ double sh[3][4];
    int lane = threadIdx.x & 63, wid = threadIdx.x >> 6;
    if (lane == 0) { sh[0][wid] = c; sh[1][wid] = l; sh[2][wid] = r; }
    __syncthreads();
    if (threadIdx.x == 0) {
        double cc = 0, ll = 0, rr = 0;
        #pragma unroll
        for (int j = 0; j < 4; ++j) { cc += sh[0][j]; ll += sh[1][j]; rr += sh[2][j]; }
        double loss = ll / cc;
        if (isnan(loss)) loss = 0.0;
        out[0] = (float)(loss + 0.5 * (rr / cc));
    }
}

extern "C" void kernel_launch(void* const* d_in, const int* in_sizes, int n_in,
                              void* d_out, int out_size, void* d_ws, size_t ws_size,
                              hipStream_t stream) {
    const float* dl    = (const float*)d_in[0];
    const float* seg_r = (const float*)d_in[1];
    const float* dlgt  = (const float*)d_in[2];
    const float* lgt   = (const float*)d_in[3];
    double* ws = (double*)d_ws;   // 4 * NBLOCKS doubles; every used slot written each call

    loss_kernel<<<NBLOCKS, TPB, 0, stream>>>(dl, seg_r, dlgt, lgt, ws);
    finalize_kernel<<<1, 256, 0, stream>>>(ws, (float*)d_out);
}